// Round 11
// baseline (593.971 us; speedup 1.0000x reference)
//
#include <hip/hip_runtime.h>
#include <hip/hip_bf16.h>

#define N_ROWS 200000
#define BM 32
#define NTILES 6250
#define TPB 4
#define NBLK ((NTILES + TPB - 1) / TPB)
#define NGRAPH 64
#define SSCALE 1.6666666666666667f
#define LOG2E 1.4426950408889634f

typedef __attribute__((ext_vector_type(8))) short short8;   // 8 bf16 (4 VGPRs)
typedef __attribute__((ext_vector_type(4))) float f32x4;    // MFMA C/D frag
typedef __attribute__((ext_vector_type(4))) unsigned int u32x4;

__device__ __forceinline__ unsigned short f2bf(float f) {
    unsigned int u = __float_as_uint(f);
    u = (u + 0x7fffu + ((u >> 16) & 1u)) >> 16;   // RNE
    return (unsigned short)u;
}
__device__ __forceinline__ unsigned int cvt_pk_bf16(float lo, float hi) {
    unsigned int r;
    asm("v_cvt_pk_bf16_f32 %0, %1, %2" : "=v"(r) : "v"(lo), "v"(hi));
    return r;
}
// fast ScaledSiLU: s*SCALE * rcp(1 + exp2(-s*log2e))
__device__ __forceinline__ float ssilu_f(float s) {
    float e = __builtin_amdgcn_exp2f(-s * LOG2E);
    return s * SSCALE * __builtin_amdgcn_rcpf(1.0f + e);
}
__device__ __forceinline__ void stage16(const float* g, float* l) {
    __builtin_amdgcn_global_load_lds(
        (__attribute__((address_space(1))) void*)(g),
        (__attribute__((address_space(3))) void*)(l), 16, 0, 0);
}

#define BAR_LGKM()  do { asm volatile("s_waitcnt lgkmcnt(0)" ::: "memory"); \
                         __builtin_amdgcn_s_barrier(); } while (0)
#define BAR_VM0()   do { asm volatile("s_waitcnt vmcnt(0) lgkmcnt(0)" ::: "memory"); \
                         __builtin_amdgcn_s_barrier(); } while (0)

// ---- fused setup: weight cvt/transpose x2, vc GEMV, sums zero + counts ----
__global__ void setup_kernel(const float* __restrict__ Wn1, const float* __restrict__ Wn2,
                             const float* __restrict__ vx, const float* __restrict__ bn1,
                             const int* __restrict__ batch,
                             unsigned short* __restrict__ wnt1x, unsigned short* __restrict__ wnt2,
                             float* __restrict__ vc, float* __restrict__ sums,
                             int* __restrict__ counts) {
    const int bid = blockIdx.x;
    const int t = threadIdx.x;
    if (bid < 256) {
        int idx = bid * 256 + t;
        int n = idx >> 8, k = idx & 255;
        wnt1x[idx] = f2bf(Wn1[k * 256 + n]);
    } else if (bid < 512) {
        int idx = (bid - 256) * 256 + t;
        int n = idx >> 8, k = idx & 255;
        wnt2[idx] = f2bf(Wn2[k * 256 + n]);
    } else if (bid < 512 + NGRAPH) {
        int b = bid - 512;
        __shared__ float vrow[256];
        vrow[t] = vx[b * 256 + t];
        __syncthreads();
        float a = bn1[t];
        #pragma unroll 8
        for (int k = 0; k < 256; ++k) a = fmaf(vrow[k], Wn1[(256 + k) * 256 + t], a);
        vc[b * 256 + t] = a;
    } else {
        int b = bid - 512 - NGRAPH;
        sums[b * 256 + t] = 0.0f;
        if (t == 0) {
            int lo = 0, hi = N_ROWS;
            while (lo < hi) { int m = (lo + hi) >> 1; if (batch[m] < b) lo = m + 1; else hi = m; }
            int lb = lo;
            lo = 0; hi = N_ROWS;
            while (lo < hi) { int m = (lo + hi) >> 1; if (batch[m] < b + 1) lo = m + 1; else hi = m; }
            counts[b] = lo - lb;
        }
    }
}

// ---- main fused node-MLP kernel: 8 waves, register-stationary weights,
//      single 48 KB LDS footprint -> 2 blocks/CU co-resident (TLP) ----
__global__ __launch_bounds__(512, 4) void node_kernel(
    const float* __restrict__ x, const int* __restrict__ batch,
    const unsigned short* __restrict__ wnt1x,  // [256][256] bf16, x-half of Wn1, N-major
    const float* __restrict__ vc,              // [64][256] per-graph bias (incl bn1)
    const unsigned short* __restrict__ wnt2,   // [256][256] bf16, N-major
    const float* __restrict__ bn2,
    float* __restrict__ hout)
{
    __shared__ float xs[BM * 256];             // f32 x tile, source-swizzled (32 KB)
    __shared__ unsigned short hb[BM * 256];    // h1 bf16, swizzled (16 KB)

    const int t = threadIdx.x;
    const int lane = t & 63;
    const int wave = t >> 6;          // 0..7
    const int lr = lane & 15;
    const int lg = lane >> 4;
    const int wcol = wave * 32;       // 32 output cols per wave

    // ---- weight slices into registers (once per block) ----
    short8 w1r[8][2], w2r[8][2];
    #pragma unroll
    for (int kk = 0; kk < 8; ++kk) {
        #pragma unroll
        for (int n = 0; n < 2; ++n) {
            int off = (wcol + n * 16 + lr) * 256 + kk * 32 + lg * 8;
            w1r[kk][n] = *reinterpret_cast<const short8*>(&wnt1x[off]);
            w2r[kk][n] = *reinterpret_cast<const short8*>(&wnt2[off]);
        }
    }
    float bn2v[2] = { bn2[wcol + lr], bn2[wcol + 16 + lr] };

    const int tile0 = blockIdx.x * TPB;
    const f32x4 zero4 = {0.f, 0.f, 0.f, 0.f};

    // ---- prologue: stage tile0 -> xs (4 rows per wave, swizzled source) ----
    {
        const float* xb = x + (size_t)tile0 * (BM * 256);
        #pragma unroll
        for (int i = 0; i < 4; ++i) {
            int row = wave * 4 + i;
            stage16(xb + row * 256 + ((lane ^ (row & 7)) << 2), &xs[row * 256]);
        }
    }
    BAR_VM0();

    #pragma unroll 1
    for (int it = 0; it < TPB; ++it) {
        const int tile = tile0 + it;
        if (tile >= NTILES) break;
        const int r0 = tile * BM;

        const bool multi = (batch[r0] != batch[r0 + BM - 1]);
        const int b0 = batch[r0];
        float vcv[2];
        if (!multi) {
            vcv[0] = vc[b0 * 256 + wcol + lr];
            vcv[1] = vc[b0 * 256 + wcol + 16 + lr];
        }

        // ---- GEMM1: A from f32 LDS (cvt_pk -> bf16), B in regs ----
        f32x4 acc[2][2];
        #pragma unroll
        for (int m = 0; m < 2; ++m)
            #pragma unroll
            for (int n = 0; n < 2; ++n) acc[m][n] = zero4;

        #pragma unroll
        for (int kk = 0; kk < 8; ++kk) {
            int c4 = kk * 8 + lg * 2;
            short8 af[2];
            #pragma unroll
            for (int m = 0; m < 2; ++m) {
                int row = m * 16 + lr;
                int s = row & 7;
                const float* rp = &xs[row * 256];
                float4 fa = *reinterpret_cast<const float4*>(rp + ((c4 ^ s) << 2));
                float4 fb = *reinterpret_cast<const float4*>(rp + (((c4 + 1) ^ s) << 2));
                u32x4 p = { cvt_pk_bf16(fa.x, fa.y), cvt_pk_bf16(fa.z, fa.w),
                            cvt_pk_bf16(fb.x, fb.y), cvt_pk_bf16(fb.z, fb.w) };
                af[m] = __builtin_bit_cast(short8, p);
            }
            #pragma unroll
            for (int m = 0; m < 2; ++m)
                #pragma unroll
                for (int n = 0; n < 2; ++n)
                    acc[m][n] = __builtin_amdgcn_mfma_f32_16x16x32_bf16(af[m], w1r[kk][n], acc[m][n], 0, 0, 0);
        }

        // ---- h1 = ssilu(acc + vc) -> hb (packed cvt, b16 writes) ----
        #pragma unroll
        for (int n = 0; n < 2; ++n) {
            int col = wcol + n * 16 + lr;
            #pragma unroll
            for (int m = 0; m < 2; ++m) {
                float hv[4];
                #pragma unroll
                for (int r = 0; r < 4; ++r) {
                    int row = m * 16 + lg * 4 + r;
                    float bias = multi ? vc[batch[r0 + row] * 256 + col] : vcv[n];
                    hv[r] = ssilu_f(acc[m][n][r] + bias);
                }
                unsigned int p01 = cvt_pk_bf16(hv[0], hv[1]);
                unsigned int p23 = cvt_pk_bf16(hv[2], hv[3]);
                int rowb = m * 16 + lg * 4;
                int e0 = ((rowb << 8) + col) ^ ((rowb & 7) << 3);
                int e1 = (((rowb + 1) << 8) + col) ^ (((rowb + 1) & 7) << 3);
                int e2 = (((rowb + 2) << 8) + col) ^ (((rowb + 2) & 7) << 3);
                int e3 = (((rowb + 3) << 8) + col) ^ (((rowb + 3) & 7) << 3);
                hb[e0] = (unsigned short)p01;
                hb[e1] = (unsigned short)(p01 >> 16);
                hb[e2] = (unsigned short)p23;
                hb[e3] = (unsigned short)(p23 >> 16);
            }
        }
        BAR_LGKM();   // hb visible; stores stay in flight

        // ---- GEMM2: A from hb (bf16), B in regs ----
        f32x4 acc2[2][2];
        #pragma unroll
        for (int m = 0; m < 2; ++m)
            #pragma unroll
            for (int n = 0; n < 2; ++n) acc2[m][n] = zero4;

        #pragma unroll
        for (int kk = 0; kk < 8; ++kk) {
            int kc = kk * 32 + lg * 8;
            short8 af[2];
            #pragma unroll
            for (int m = 0; m < 2; ++m) {
                int row = m * 16 + lr;
                int e = ((row << 8) + kc) ^ ((row & 7) << 3);
                af[m] = *reinterpret_cast<const short8*>(&hb[e]);
            }
            #pragma unroll
            for (int m = 0; m < 2; ++m)
                #pragma unroll
                for (int n = 0; n < 2; ++n)
                    acc2[m][n] = __builtin_amdgcn_mfma_f32_16x16x32_bf16(af[m], w2r[kk][n], acc2[m][n], 0, 0, 0);
        }

        // ---- epilogue: h = ssilu(acc2 + bn2) + x (exact f32 from LDS) ; stores ----
        #pragma unroll
        for (int n = 0; n < 2; ++n) {
            int col = wcol + n * 16 + lr;
            int c4r = col >> 2, c3 = col & 3;
            float bias = bn2v[n];
            #pragma unroll
            for (int m = 0; m < 2; ++m) {
                #pragma unroll
                for (int r = 0; r < 4; ++r) {
                    int row = m * 16 + lg * 4 + r;
                    float xv = xs[row * 256 + (((c4r ^ (row & 7))) << 2) + c3];
                    float hv = ssilu_f(acc2[m][n][r] + bias) + xv;
                    hout[(size_t)(r0 + row) * 256 + col] = hv;
                }
            }
        }

        // ---- restage xs for next tile (single buffer) ----
        if (it < TPB - 1 && tile + 1 < NTILES) {
            BAR_LGKM();   // all waves' ds_reads of xs retired -> safe to overwrite
            const float* xb = x + (size_t)(tile + 1) * (BM * 256);
            #pragma unroll
            for (int i = 0; i < 4; ++i) {
                int row = wave * 4 + i;
                stage16(xb + row * 256 + ((lane ^ (row & 7)) << 2), &xs[row * 256]);
            }
            BAR_VM0();    // stage complete (drains stores too; other block's compute covers)
        }
    }
}

// ---- pooling: 64 graphs x 8 row-chunks; register accumulate, 1 atomic/col/block ----
__global__ __launch_bounds__(256, 8) void pool_kernel(
    const float* __restrict__ h, const int* __restrict__ batch,
    float* __restrict__ sums)
{
    const int b = blockIdx.x >> 3;
    const int j = blockIdx.x & 7;
    const int t = threadIdx.x;

    int lo = 0, hi = N_ROWS;
    while (lo < hi) { int m = (lo + hi) >> 1; if (batch[m] < b) lo = m + 1; else hi = m; }
    const int lb = lo;
    lo = 0; hi = N_ROWS;
    while (lo < hi) { int m = (lo + hi) >> 1; if (batch[m] < b + 1) lo = m + 1; else hi = m; }
    const int ub = lo;

    float a0 = 0.f, a1 = 0.f, a2 = 0.f, a3 = 0.f;
    int r = lb + j;
    for (; r + 24 < ub; r += 32) {
        a0 += h[(size_t)(r)      * 256 + t];
        a1 += h[(size_t)(r + 8)  * 256 + t];
        a2 += h[(size_t)(r + 16) * 256 + t];
        a3 += h[(size_t)(r + 24) * 256 + t];
    }
    for (; r < ub; r += 8) a0 += h[(size_t)r * 256 + t];
    float acc = (a0 + a1) + (a2 + a3);
    atomicAdd(&sums[b * 256 + t], acc);
}

// ---- virtual-node MLP layer 1: v = ssilu(cat(pooled, vx) @ Wv1 + bv1) ----
__global__ void vmlp1(const float* __restrict__ sums, const int* __restrict__ counts,
                      const float* __restrict__ vx, const float* __restrict__ Wv1,
                      const float* __restrict__ bv1, float* __restrict__ v) {
    __shared__ float cat[512];
    int b = blockIdx.x, t = threadIdx.x;
    float cnt = fmaxf((float)counts[b], 1.0f);
    cat[t] = sums[b * 256 + t] / cnt;
    cat[t + 256] = vx[b * 256 + t];
    __syncthreads();
    float a = 0.f;
    #pragma unroll 8
    for (int k = 0; k < 512; ++k) a = fmaf(cat[k], Wv1[k * 256 + t], a);
    a += bv1[t];
    v[b * 256 + t] = ssilu_f(a);
}

// ---- virtual-node MLP layer 2: vx_new = ssilu(v @ Wv2 + bv2) ----
__global__ void vmlp2(const float* __restrict__ v, const float* __restrict__ Wv2,
                      const float* __restrict__ bv2, float* __restrict__ out) {
    __shared__ float rowv[256];
    int b = blockIdx.x, t = threadIdx.x;
    rowv[t] = v[b * 256 + t];
    __syncthreads();
    float a = 0.f;
    #pragma unroll 8
    for (int k = 0; k < 256; ++k) a = fmaf(rowv[k], Wv2[k * 256 + t], a);
    a += bv2[t];
    out[b * 256 + t] = ssilu_f(a);
}

extern "C" void kernel_launch(void* const* d_in, const int* in_sizes, int n_in,
                              void* d_out, int out_size, void* d_ws, size_t ws_size,
                              hipStream_t stream) {
    const float* x   = (const float*)d_in[0];
    const int*   batch = (const int*)d_in[1];
    const float* vx  = (const float*)d_in[2];
    const float* Wn1 = (const float*)d_in[3];
    const float* bn1 = (const float*)d_in[4];
    const float* Wn2 = (const float*)d_in[5];
    const float* bn2 = (const float*)d_in[6];
    const float* Wv1 = (const float*)d_in[7];
    const float* bv1 = (const float*)d_in[8];
    const float* Wv2 = (const float*)d_in[9];
    const float* bv2 = (const float*)d_in[10];

    float* hout = (float*)d_out;
    float* vout = hout + (size_t)N_ROWS * 256;   // also reused as v-scratch

    // ws layout — total 393,472 B
    char* ws = (char*)d_ws;
    unsigned short* wnt1x  = (unsigned short*)(ws);           // 256*256*2 = 131072
    unsigned short* wnt2   = (unsigned short*)(ws + 131072);  // 131072
    float*          vc     = (float*)(ws + 262144);           // 64*256*4  = 65536
    float*          sums   = (float*)(ws + 327680);           // 65536
    int*            counts = (int*)(ws + 393216);             // 256

    setup_kernel<<<512 + 2 * NGRAPH, 256, 0, stream>>>(Wn1, Wn2, vx, bn1, batch,
                                                       wnt1x, wnt2, vc, sums, counts);
    node_kernel<<<NBLK, 512, 0, stream>>>(x, batch, wnt1x, vc, wnt2, bn2, hout);
    pool_kernel<<<NGRAPH * 8, 256, 0, stream>>>(hout, batch, sums);
    vmlp1<<<NGRAPH, 256, 0, stream>>>(sums, counts, vx, Wv1, bv1, vout);
    vmlp2<<<NGRAPH, 256, 0, stream>>>(vout, Wv2, bv2, vout);
}

// Round 12
// 332.234 us; speedup vs baseline: 1.7878x; 1.7878x over previous
//
#include <hip/hip_runtime.h>
#include <hip/hip_bf16.h>

#define N_ROWS 200000
#define BM 64
#define NTILES 3125
#define NGRAPH 64
#define SSCALE 1.6666666666666667f
#define LOG2E 1.4426950408889634f

typedef __attribute__((ext_vector_type(8))) short short8;   // 8 bf16 (4 VGPRs)
typedef __attribute__((ext_vector_type(4))) float f32x4;    // MFMA C/D frag
typedef __attribute__((ext_vector_type(4))) unsigned int u32x4;

__device__ __forceinline__ unsigned short f2bf(float f) {
    unsigned int u = __float_as_uint(f);
    u = (u + 0x7fffu + ((u >> 16) & 1u)) >> 16;   // RNE
    return (unsigned short)u;
}
__device__ __forceinline__ float bf2f(unsigned short v) {
    return __uint_as_float(((unsigned int)v) << 16);
}
__device__ __forceinline__ unsigned int cvt_pk_bf16(float lo, float hi) {
    unsigned int r;
    asm("v_cvt_pk_bf16_f32 %0, %1, %2" : "=v"(r) : "v"(lo), "v"(hi));
    return r;
}
// fast ScaledSiLU: s*SCALE * rcp(1 + exp2(-s*log2e))
__device__ __forceinline__ float ssilu_f(float s) {
    float e = __builtin_amdgcn_exp2f(-s * LOG2E);
    return s * SSCALE * __builtin_amdgcn_rcpf(1.0f + e);
}

// ---- fused setup: weight cvt/transpose x2, vc GEMV, sums zero + counts ----
__global__ void setup_kernel(const float* __restrict__ Wn1, const float* __restrict__ Wn2,
                             const float* __restrict__ vx, const float* __restrict__ bn1,
                             const int* __restrict__ batch,
                             unsigned short* __restrict__ wnt1x, unsigned short* __restrict__ wnt2,
                             float* __restrict__ vc, float* __restrict__ sums,
                             int* __restrict__ counts) {
    const int bid = blockIdx.x;
    const int t = threadIdx.x;
    if (bid < 256) {
        int idx = bid * 256 + t;
        int n = idx >> 8, k = idx & 255;
        wnt1x[idx] = f2bf(Wn1[k * 256 + n]);
    } else if (bid < 512) {
        int idx = (bid - 256) * 256 + t;
        int n = idx >> 8, k = idx & 255;
        wnt2[idx] = f2bf(Wn2[k * 256 + n]);
    } else if (bid < 512 + NGRAPH) {
        int b = bid - 512;
        __shared__ float vrow[256];
        vrow[t] = vx[b * 256 + t];
        __syncthreads();
        float a = bn1[t];
        #pragma unroll 8
        for (int k = 0; k < 256; ++k) a = fmaf(vrow[k], Wn1[(256 + k) * 256 + t], a);
        vc[b * 256 + t] = a;
    } else {
        int b = bid - 512 - NGRAPH;
        sums[b * 256 + t] = 0.0f;
        if (t == 0) {
            int lo = 0, hi = N_ROWS;
            while (lo < hi) { int m = (lo + hi) >> 1; if (batch[m] < b) lo = m + 1; else hi = m; }
            int lb = lo;
            lo = 0; hi = N_ROWS;
            while (lo < hi) { int m = (lo + hi) >> 1; if (batch[m] < b + 1) lo = m + 1; else hi = m; }
            counts[b] = lo - lb;
        }
    }
}

// ---- main fused node-MLP kernel: 64-row tile, 4 waves x 64 cols each,
//      16 MFMA per wave per K-step; weights from L2 (compiler-pipelined) ----
__global__ __launch_bounds__(256, 2) void node_kernel(
    const float* __restrict__ x, const int* __restrict__ batch,
    const unsigned short* __restrict__ wnt1x,  // [256][256] bf16, x-half of Wn1, N-major
    const float* __restrict__ vc,              // [64][256] per-graph bias (incl bn1)
    const unsigned short* __restrict__ wnt2,   // [256][256] bf16, N-major
    const float* __restrict__ bn2,
    float* __restrict__ hout)
{
    __shared__ unsigned short xa[BM * 256];   // x tile bf16, swizzled (32 KB)
    __shared__ unsigned short hb[BM * 256];   // h1 tile bf16, swizzled (32 KB)

    const int t = threadIdx.x;
    const int lane = t & 63;
    const int wave = t >> 6;          // 0..3
    const int lr = lane & 15;
    const int lg = lane >> 4;
    const int wcol = wave * 64;       // 64 output cols per wave
    const int r0 = blockIdx.x * BM;

    // ---- stage: x tile (64x256 f32) -> LDS bf16 (swizzled), cvt_pk ----
    #pragma unroll
    for (int i = 0; i < 16; ++i) {
        int flat = (t + i * 256) * 4;           // element in 64x256 tile
        int row = flat >> 8, col = flat & 255;
        float4 v = *reinterpret_cast<const float4*>(&x[(size_t)r0 * 256 + flat]);
        int e = ((row << 8) + col) ^ ((row & 7) << 3);
        unsigned int p01 = cvt_pk_bf16(v.x, v.y);
        unsigned int p23 = cvt_pk_bf16(v.z, v.w);
        ushort4 u;
        u.x = (unsigned short)p01; u.y = (unsigned short)(p01 >> 16);
        u.z = (unsigned short)p23; u.w = (unsigned short)(p23 >> 16);
        *reinterpret_cast<ushort4*>(&xa[e]) = u;
    }
    __syncthreads();

    const f32x4 zero4 = {0.f, 0.f, 0.f, 0.f};
    const bool multi = (batch[r0] != batch[r0 + BM - 1]);
    const int b0 = batch[r0];
    float vcv[4];
    if (!multi) {
        #pragma unroll
        for (int n = 0; n < 4; ++n) vcv[n] = vc[b0 * 256 + wcol + n * 16 + lr];
    }

    // ---- GEMM1: [64x256] @ [256 x 64-per-wave] ----
    f32x4 acc[4][4];
    #pragma unroll
    for (int m = 0; m < 4; ++m)
        #pragma unroll
        for (int n = 0; n < 4; ++n) acc[m][n] = zero4;

    #pragma unroll
    for (int kk = 0; kk < 8; ++kk) {
        int kc = kk * 32 + lg * 8;
        short8 bfr[4];
        #pragma unroll
        for (int n = 0; n < 4; ++n)
            bfr[n] = *reinterpret_cast<const short8*>(&wnt1x[(wcol + n * 16 + lr) * 256 + kc]);
        short8 af[4];
        #pragma unroll
        for (int m = 0; m < 4; ++m) {
            int row = m * 16 + lr;
            int e = ((row << 8) + kc) ^ ((row & 7) << 3);
            af[m] = *reinterpret_cast<const short8*>(&xa[e]);
        }
        #pragma unroll
        for (int m = 0; m < 4; ++m)
            #pragma unroll
            for (int n = 0; n < 4; ++n)
                acc[m][n] = __builtin_amdgcn_mfma_f32_16x16x32_bf16(af[m], bfr[n], acc[m][n], 0, 0, 0);
    }

    // ---- h1 = ssilu(acc + vc) -> hb (packed cvt) ----
    #pragma unroll
    for (int n = 0; n < 4; ++n) {
        int col = wcol + n * 16 + lr;
        #pragma unroll
        for (int m = 0; m < 4; ++m) {
            float hv[4];
            #pragma unroll
            for (int r = 0; r < 4; ++r) {
                int row = m * 16 + lg * 4 + r;
                float bias = multi ? vc[batch[r0 + row] * 256 + col] : vcv[n];
                hv[r] = ssilu_f(acc[m][n][r] + bias);
            }
            unsigned int p01 = cvt_pk_bf16(hv[0], hv[1]);
            unsigned int p23 = cvt_pk_bf16(hv[2], hv[3]);
            int rowb = m * 16 + lg * 4;
            int e0 = ((rowb << 8) + col) ^ ((rowb & 7) << 3);
            int e1 = (((rowb + 1) << 8) + col) ^ (((rowb + 1) & 7) << 3);
            int e2 = (((rowb + 2) << 8) + col) ^ (((rowb + 2) & 7) << 3);
            int e3 = (((rowb + 3) << 8) + col) ^ (((rowb + 3) & 7) << 3);
            hb[e0] = (unsigned short)p01;
            hb[e1] = (unsigned short)(p01 >> 16);
            hb[e2] = (unsigned short)p23;
            hb[e3] = (unsigned short)(p23 >> 16);
        }
    }
    __syncthreads();

    // ---- GEMM2: [64x256] @ [256 x 64-per-wave] ----
    f32x4 acc2[4][4];
    #pragma unroll
    for (int m = 0; m < 4; ++m)
        #pragma unroll
        for (int n = 0; n < 4; ++n) acc2[m][n] = zero4;

    #pragma unroll
    for (int kk = 0; kk < 8; ++kk) {
        int kc = kk * 32 + lg * 8;
        short8 bfr[4];
        #pragma unroll
        for (int n = 0; n < 4; ++n)
            bfr[n] = *reinterpret_cast<const short8*>(&wnt2[(wcol + n * 16 + lr) * 256 + kc]);
        short8 af[4];
        #pragma unroll
        for (int m = 0; m < 4; ++m) {
            int row = m * 16 + lr;
            int e = ((row << 8) + kc) ^ ((row & 7) << 3);
            af[m] = *reinterpret_cast<const short8*>(&hb[e]);
        }
        #pragma unroll
        for (int m = 0; m < 4; ++m)
            #pragma unroll
            for (int n = 0; n < 4; ++n)
                acc2[m][n] = __builtin_amdgcn_mfma_f32_16x16x32_bf16(af[m], bfr[n], acc2[m][n], 0, 0, 0);
    }

    // ---- epilogue: h = ssilu(acc2 + bn2) + x (bf16 from LDS) ; plain stores ----
    #pragma unroll
    for (int n = 0; n < 4; ++n) {
        int col = wcol + n * 16 + lr;
        float bias = bn2[col];
        #pragma unroll
        for (int m = 0; m < 4; ++m) {
            #pragma unroll
            for (int r = 0; r < 4; ++r) {
                int row = m * 16 + lg * 4 + r;
                int e = ((row << 8) + col) ^ ((row & 7) << 3);
                float hv = ssilu_f(acc2[m][n][r] + bias) + bf2f(xa[e]);
                hout[(size_t)(r0 + row) * 256 + col] = hv;
            }
        }
    }
}

// ---- pooling: 64 graphs x 8 row-chunks; register accumulate, 1 atomic/col/block ----
__global__ __launch_bounds__(256, 8) void pool_kernel(
    const float* __restrict__ h, const int* __restrict__ batch,
    float* __restrict__ sums)
{
    const int b = blockIdx.x >> 3;
    const int j = blockIdx.x & 7;
    const int t = threadIdx.x;

    int lo = 0, hi = N_ROWS;
    while (lo < hi) { int m = (lo + hi) >> 1; if (batch[m] < b) lo = m + 1; else hi = m; }
    const int lb = lo;
    lo = 0; hi = N_ROWS;
    while (lo < hi) { int m = (lo + hi) >> 1; if (batch[m] < b + 1) lo = m + 1; else hi = m; }
    const int ub = lo;

    float a0 = 0.f, a1 = 0.f, a2 = 0.f, a3 = 0.f;
    int r = lb + j;
    for (; r + 24 < ub; r += 32) {
        a0 += h[(size_t)(r)      * 256 + t];
        a1 += h[(size_t)(r + 8)  * 256 + t];
        a2 += h[(size_t)(r + 16) * 256 + t];
        a3 += h[(size_t)(r + 24) * 256 + t];
    }
    for (; r < ub; r += 8) a0 += h[(size_t)r * 256 + t];
    float acc = (a0 + a1) + (a2 + a3);
    atomicAdd(&sums[b * 256 + t], acc);
}

// ---- virtual-node MLP layer 1: v = ssilu(cat(pooled, vx) @ Wv1 + bv1) ----
__global__ void vmlp1(const float* __restrict__ sums, const int* __restrict__ counts,
                      const float* __restrict__ vx, const float* __restrict__ Wv1,
                      const float* __restrict__ bv1, float* __restrict__ v) {
    __shared__ float cat[512];
    int b = blockIdx.x, t = threadIdx.x;
    float cnt = fmaxf((float)counts[b], 1.0f);
    cat[t] = sums[b * 256 + t] / cnt;
    cat[t + 256] = vx[b * 256 + t];
    __syncthreads();
    float a = 0.f;
    #pragma unroll 8
    for (int k = 0; k < 512; ++k) a = fmaf(cat[k], Wv1[k * 256 + t], a);
    a += bv1[t];
    v[b * 256 + t] = ssilu_f(a);
}

// ---- virtual-node MLP layer 2: vx_new = ssilu(v @ Wv2 + bv2) ----
__global__ void vmlp2(const float* __restrict__ v, const float* __restrict__ Wv2,
                      const float* __restrict__ bv2, float* __restrict__ out) {
    __shared__ float rowv[256];
    int b = blockIdx.x, t = threadIdx.x;
    rowv[t] = v[b * 256 + t];
    __syncthreads();
    float a = 0.f;
    #pragma unroll 8
    for (int k = 0; k < 256; ++k) a = fmaf(rowv[k], Wv2[k * 256 + t], a);
    a += bv2[t];
    out[b * 256 + t] = ssilu_f(a);
}

extern "C" void kernel_launch(void* const* d_in, const int* in_sizes, int n_in,
                              void* d_out, int out_size, void* d_ws, size_t ws_size,
                              hipStream_t stream) {
    const float* x   = (const float*)d_in[0];
    const int*   batch = (const int*)d_in[1];
    const float* vx  = (const float*)d_in[2];
    const float* Wn1 = (const float*)d_in[3];
    const float* bn1 = (const float*)d_in[4];
    const float* Wn2 = (const float*)d_in[5];
    const float* bn2 = (const float*)d_in[6];
    const float* Wv1 = (const float*)d_in[7];
    const float* bv1 = (const float*)d_in[8];
    const float* Wv2 = (const float*)d_in[9];
    const float* bv2 = (const float*)d_in[10];

    float* hout = (float*)d_out;
    float* vout = hout + (size_t)N_ROWS * 256;   // also reused as v-scratch

    // ws layout — total 393,472 B
    char* ws = (char*)d_ws;
    unsigned short* wnt1x  = (unsigned short*)(ws);           // 256*256*2 = 131072
    unsigned short* wnt2   = (unsigned short*)(ws + 131072);  // 131072
    float*          vc     = (float*)(ws + 262144);           // 64*256*4  = 65536
    float*          sums   = (float*)(ws + 327680);           // 65536
    int*            counts = (int*)(ws + 393216);             // 256

    setup_kernel<<<512 + 2 * NGRAPH, 256, 0, stream>>>(Wn1, Wn2, vx, bn1, batch,
                                                       wnt1x, wnt2, vc, sums, counts);
    node_kernel<<<NTILES, 256, 0, stream>>>(x, batch, wnt1x, vc, wnt2, bn2, hout);
    pool_kernel<<<NGRAPH * 8, 256, 0, stream>>>(hout, batch, sums);
    vmlp1<<<NGRAPH, 256, 0, stream>>>(sums, counts, vx, Wv1, bv1, vout);
    vmlp2<<<NGRAPH, 256, 0, stream>>>(vout, Wv2, bv2, vout);
}

// Round 13
// 274.648 us; speedup vs baseline: 2.1627x; 1.2097x over previous
//
#include <hip/hip_runtime.h>
#include <hip/hip_bf16.h>

#define N_ROWS 200000
#define BM 32
#define NTILES 6250
#define TPB 4
#define NBLK ((NTILES + TPB - 1) / TPB)
#define NGRAPH 64
#define SSCALE 1.6666666666666667f
#define LOG2E 1.4426950408889634f

typedef __attribute__((ext_vector_type(8))) short short8;   // 8 bf16 (4 VGPRs)
typedef __attribute__((ext_vector_type(4))) float f32x4;    // MFMA C/D frag

__device__ __forceinline__ unsigned short f2bf(float f) {
    unsigned int u = __float_as_uint(f);
    u = (u + 0x7fffu + ((u >> 16) & 1u)) >> 16;   // RNE
    return (unsigned short)u;
}
__device__ __forceinline__ float bf2f(unsigned short v) {
    return __uint_as_float(((unsigned int)v) << 16);
}
__device__ __forceinline__ unsigned int cvt_pk_bf16(float lo, float hi) {
    unsigned int r;
    asm("v_cvt_pk_bf16_f32 %0, %1, %2" : "=v"(r) : "v"(lo), "v"(hi));
    return r;
}
// fast ScaledSiLU: s*SCALE * rcp(1 + exp2(-s*log2e))
__device__ __forceinline__ float ssilu_f(float s) {
    float e = __builtin_amdgcn_exp2f(-s * LOG2E);
    return s * SSCALE * __builtin_amdgcn_rcpf(1.0f + e);
}

// lgkmcnt-only barrier: LDS ops retired, global stores stay in flight
#define BAR_LGKM()  do { asm volatile("s_waitcnt lgkmcnt(0)" ::: "memory"); \
                         __builtin_amdgcn_s_barrier(); } while (0)

// ---- fused setup: weight cvt/transpose x2, vc GEMV, sums zero + counts ----
__global__ void setup_kernel(const float* __restrict__ Wn1, const float* __restrict__ Wn2,
                             const float* __restrict__ vx, const float* __restrict__ bn1,
                             const int* __restrict__ batch,
                             unsigned short* __restrict__ wnt1x, unsigned short* __restrict__ wnt2,
                             float* __restrict__ vc, float* __restrict__ sums,
                             int* __restrict__ counts) {
    const int bid = blockIdx.x;
    const int t = threadIdx.x;
    if (bid < 256) {
        int idx = bid * 256 + t;
        int n = idx >> 8, k = idx & 255;
        wnt1x[idx] = f2bf(Wn1[k * 256 + n]);
    } else if (bid < 512) {
        int idx = (bid - 256) * 256 + t;
        int n = idx >> 8, k = idx & 255;
        wnt2[idx] = f2bf(Wn2[k * 256 + n]);
    } else if (bid < 512 + NGRAPH) {
        int b = bid - 512;
        __shared__ float vrow[256];
        vrow[t] = vx[b * 256 + t];
        __syncthreads();
        float a = bn1[t];
        #pragma unroll 8
        for (int k = 0; k < 256; ++k) a = fmaf(vrow[k], Wn1[(256 + k) * 256 + t], a);
        vc[b * 256 + t] = a;
    } else {
        int b = bid - 512 - NGRAPH;
        sums[b * 256 + t] = 0.0f;
        if (t == 0) {
            int lo = 0, hi = N_ROWS;
            while (lo < hi) { int m = (lo + hi) >> 1; if (batch[m] < b) lo = m + 1; else hi = m; }
            int lb = lo;
            lo = 0; hi = N_ROWS;
            while (lo < hi) { int m = (lo + hi) >> 1; if (batch[m] < b + 1) lo = m + 1; else hi = m; }
            counts[b] = lo - lb;
        }
    }
}

// ---- main fused node-MLP kernel: 8 waves x 32 cols, register-stationary weights,
//      bf16 reg-staged x (double-buffered), fused pooling partials, no vmcnt waits ----
__global__ __launch_bounds__(512, 2) void node_kernel(
    const float* __restrict__ x, const int* __restrict__ batch,
    const unsigned short* __restrict__ wnt1x,  // [256][256] bf16, x-half of Wn1, N-major
    const float* __restrict__ vc,              // [64][256] per-graph bias (incl bn1)
    const unsigned short* __restrict__ wnt2,   // [256][256] bf16, N-major
    const float* __restrict__ bn2,
    float* __restrict__ hout, float* __restrict__ sums)
{
    __shared__ unsigned short xa[2][BM * 256]; // x tiles bf16, swizzled (2x16 KB)
    __shared__ unsigned short hb[BM * 256];    // h1 bf16, swizzled (16 KB)

    const int t = threadIdx.x;
    const int lane = t & 63;
    const int wave = t >> 6;          // 0..7
    const int lr = lane & 15;
    const int lg = lane >> 4;
    const int wcol = wave * 32;       // 32 output cols per wave

    // ---- weight slices into registers (once per block) ----
    short8 w1r[8][2], w2r[8][2];
    #pragma unroll
    for (int kk = 0; kk < 8; ++kk) {
        #pragma unroll
        for (int n = 0; n < 2; ++n) {
            int off = (wcol + n * 16 + lr) * 256 + kk * 32 + lg * 8;
            w1r[kk][n] = *reinterpret_cast<const short8*>(&wnt1x[off]);
            w2r[kk][n] = *reinterpret_cast<const short8*>(&wnt2[off]);
        }
    }
    float bn2v[2] = { bn2[wcol + lr], bn2[wcol + 16 + lr] };

    const int tile0 = blockIdx.x * TPB;
    const int blk_r0 = tile0 * BM;
    const int blk_rlast = min(blk_r0 + TPB * BM - 1, N_ROWS - 1);
    const int g0 = batch[blk_r0];
    const bool blk_multi = (batch[blk_rlast] != g0);
    float pa[2] = {0.f, 0.f}, pb[2] = {0.f, 0.f};   // pooled partials: graph g0, g0+1

    const f32x4 zero4 = {0.f, 0.f, 0.f, 0.f};

    // ---- prologue: load tile0's x into regs ----
    float4 vreg[4];
    {
        const float4* xp = reinterpret_cast<const float4*>(x + (size_t)tile0 * (BM * 256));
        #pragma unroll
        for (int i = 0; i < 4; ++i) vreg[i] = xp[t + i * 512];
    }

    int cur = 0;
    #pragma unroll 1
    for (int it = 0; it < TPB; ++it) {
        const int tile = tile0 + it;
        if (tile >= NTILES) break;
        const int r0 = tile * BM;

        // ---- write staged regs -> xa[cur] as bf16 (swizzled) ----
        #pragma unroll
        for (int i = 0; i < 4; ++i) {
            int flat = (t + i * 512) * 4;           // element in 32x256 tile
            int row = flat >> 8, col = flat & 255;
            int e = ((row << 8) + col) ^ ((row & 7) << 3);
            unsigned int p01 = cvt_pk_bf16(vreg[i].x, vreg[i].y);
            unsigned int p23 = cvt_pk_bf16(vreg[i].z, vreg[i].w);
            ushort4 u;
            u.x = (unsigned short)p01; u.y = (unsigned short)(p01 >> 16);
            u.z = (unsigned short)p23; u.w = (unsigned short)(p23 >> 16);
            *reinterpret_cast<ushort4*>(&xa[cur][e]) = u;
        }

        // ---- issue NEXT tile's loads (regs free; full tile to cover latency) ----
        if (it < TPB - 1 && tile + 1 < NTILES) {
            const float4* xp = reinterpret_cast<const float4*>(x + (size_t)(tile + 1) * (BM * 256));
            #pragma unroll
            for (int i = 0; i < 4; ++i) vreg[i] = xp[t + i * 512];
        }

        BAR_LGKM();   // xa[cur] visible to all waves

        const bool multi = (batch[r0] != batch[r0 + BM - 1]);
        const int tg = batch[r0];
        float vcv[2];
        if (!multi) {
            vcv[0] = vc[tg * 256 + wcol + lr];
            vcv[1] = vc[tg * 256 + wcol + 16 + lr];
        }

        // ---- GEMM1: A from xa[cur] (bf16), B in regs ----
        f32x4 acc[2][2];
        #pragma unroll
        for (int m = 0; m < 2; ++m)
            #pragma unroll
            for (int n = 0; n < 2; ++n) acc[m][n] = zero4;

        #pragma unroll
        for (int kk = 0; kk < 8; ++kk) {
            int kc = kk * 32 + lg * 8;
            short8 af[2];
            #pragma unroll
            for (int m = 0; m < 2; ++m) {
                int row = m * 16 + lr;
                int e = ((row << 8) + kc) ^ ((row & 7) << 3);
                af[m] = *reinterpret_cast<const short8*>(&xa[cur][e]);
            }
            #pragma unroll
            for (int m = 0; m < 2; ++m)
                #pragma unroll
                for (int n = 0; n < 2; ++n)
                    acc[m][n] = __builtin_amdgcn_mfma_f32_16x16x32_bf16(af[m], w1r[kk][n], acc[m][n], 0, 0, 0);
        }

        // ---- h1 = ssilu(acc + vc) -> hb (packed cvt, b16 writes) ----
        #pragma unroll
        for (int n = 0; n < 2; ++n) {
            int col = wcol + n * 16 + lr;
            #pragma unroll
            for (int m = 0; m < 2; ++m) {
                float hv[4];
                #pragma unroll
                for (int r = 0; r < 4; ++r) {
                    int row = m * 16 + lg * 4 + r;
                    float bias = multi ? vc[batch[r0 + row] * 256 + col] : vcv[n];
                    hv[r] = ssilu_f(acc[m][n][r] + bias);
                }
                unsigned int p01 = cvt_pk_bf16(hv[0], hv[1]);
                unsigned int p23 = cvt_pk_bf16(hv[2], hv[3]);
                int rowb = m * 16 + lg * 4;
                int e0 = ((rowb << 8) + col) ^ ((rowb & 7) << 3);
                int e1 = (((rowb + 1) << 8) + col) ^ (((rowb + 1) & 7) << 3);
                int e2 = (((rowb + 2) << 8) + col) ^ (((rowb + 2) & 7) << 3);
                int e3 = (((rowb + 3) << 8) + col) ^ (((rowb + 3) & 7) << 3);
                hb[e0] = (unsigned short)p01;
                hb[e1] = (unsigned short)(p01 >> 16);
                hb[e2] = (unsigned short)p23;
                hb[e3] = (unsigned short)(p23 >> 16);
            }
        }
        BAR_LGKM();   // hb visible; stores from prior tiles stay in flight

        // ---- GEMM2: A from hb (bf16), B in regs ----
        f32x4 acc2[2][2];
        #pragma unroll
        for (int m = 0; m < 2; ++m)
            #pragma unroll
            for (int n = 0; n < 2; ++n) acc2[m][n] = zero4;

        #pragma unroll
        for (int kk = 0; kk < 8; ++kk) {
            int kc = kk * 32 + lg * 8;
            short8 af[2];
            #pragma unroll
            for (int m = 0; m < 2; ++m) {
                int row = m * 16 + lr;
                int e = ((row << 8) + kc) ^ ((row & 7) << 3);
                af[m] = *reinterpret_cast<const short8*>(&hb[e]);
            }
            #pragma unroll
            for (int m = 0; m < 2; ++m)
                #pragma unroll
                for (int n = 0; n < 2; ++n)
                    acc2[m][n] = __builtin_amdgcn_mfma_f32_16x16x32_bf16(af[m], w2r[kk][n], acc2[m][n], 0, 0, 0);
        }

        // ---- epilogue: h = ssilu(acc2+bn2) + x ; store + pooled partial accumulate ----
        #pragma unroll
        for (int n = 0; n < 2; ++n) {
            int col = wcol + n * 16 + lr;
            float bias = bn2v[n];
            #pragma unroll
            for (int m = 0; m < 2; ++m) {
                #pragma unroll
                for (int r = 0; r < 4; ++r) {
                    int row = m * 16 + lg * 4 + r;
                    int e = ((row << 8) + col) ^ ((row & 7) << 3);
                    float hv = ssilu_f(acc2[m][n][r] + bias) + bf2f(xa[cur][e]);
                    hout[(size_t)(r0 + row) * 256 + col] = hv;
                    if (!blk_multi) {
                        pa[n] += hv;                       // whole block one graph
                    } else if (!multi) {
                        if (tg == g0) pa[n] += hv; else pb[n] += hv;   // uniform branch
                    } else {
                        if (batch[r0 + row] == g0) pa[n] += hv; else pb[n] += hv;
                    }
                }
            }
        }
        BAR_LGKM();   // all residual reads of xa[cur] + GEMM2 reads of hb retired
        cur ^= 1;
    }

    // ---- block-level pooled partial: wave shfl-reduce, then one atomic per col ----
    #pragma unroll
    for (int n = 0; n < 2; ++n) {
        float p = pa[n];
        p += __shfl_xor(p, 16);
        p += __shfl_xor(p, 32);
        if (lane < 16) atomicAdd(&sums[g0 * 256 + wcol + n * 16 + lane], p);
    }
    if (blk_multi) {
        #pragma unroll
        for (int n = 0; n < 2; ++n) {
            float p = pb[n];
            p += __shfl_xor(p, 16);
            p += __shfl_xor(p, 32);
            if (lane < 16 && g0 + 1 < NGRAPH)
                atomicAdd(&sums[(g0 + 1) * 256 + wcol + n * 16 + lane], p);
        }
    }
}

// ---- virtual-node MLP layer 1: v = ssilu(cat(pooled, vx) @ Wv1 + bv1) ----
__global__ void vmlp1(const float* __restrict__ sums, const int* __restrict__ counts,
                      const float* __restrict__ vx, const float* __restrict__ Wv1,
                      const float* __restrict__ bv1, float* __restrict__ v) {
    __shared__ float cat[512];
    int b = blockIdx.x, t = threadIdx.x;
    float cnt = fmaxf((float)counts[b], 1.0f);
    cat[t] = sums[b * 256 + t] / cnt;
    cat[t + 256] = vx[b * 256 + t];
    __syncthreads();
    float a = 0.f;
    #pragma unroll 8
    for (int k = 0; k < 512; ++k) a = fmaf(cat[k], Wv1[k * 256 + t], a);
    a += bv1[t];
    v[b * 256 + t] = ssilu_f(a);
}

// ---- virtual-node MLP layer 2: vx_new = ssilu(v @ Wv2 + bv2) ----
__global__ void vmlp2(const float* __restrict__ v, const float* __restrict__ Wv2,
                      const float* __restrict__ bv2, float* __restrict__ out) {
    __shared__ float rowv[256];
    int b = blockIdx.x, t = threadIdx.x;
    rowv[t] = v[b * 256 + t];
    __syncthreads();
    float a = 0.f;
    #pragma unroll 8
    for (int k = 0; k < 256; ++k) a = fmaf(rowv[k], Wv2[k * 256 + t], a);
    a += bv2[t];
    out[b * 256 + t] = ssilu_f(a);
}

extern "C" void kernel_launch(void* const* d_in, const int* in_sizes, int n_in,
                              void* d_out, int out_size, void* d_ws, size_t ws_size,
                              hipStream_t stream) {
    const float* x   = (const float*)d_in[0];
    const int*   batch = (const int*)d_in[1];
    const float* vx  = (const float*)d_in[2];
    const float* Wn1 = (const float*)d_in[3];
    const float* bn1 = (const float*)d_in[4];
    const float* Wn2 = (const float*)d_in[5];
    const float* bn2 = (const float*)d_in[6];
    const float* Wv1 = (const float*)d_in[7];
    const float* bv1 = (const float*)d_in[8];
    const float* Wv2 = (const float*)d_in[9];
    const float* bv2 = (const float*)d_in[10];

    float* hout = (float*)d_out;
    float* vout = hout + (size_t)N_ROWS * 256;   // also reused as v-scratch

    // ws layout — total 393,472 B
    char* ws = (char*)d_ws;
    unsigned short* wnt1x  = (unsigned short*)(ws);           // 256*256*2 = 131072
    unsigned short* wnt2   = (unsigned short*)(ws + 131072);  // 131072
    float*          vc     = (float*)(ws + 262144);           // 64*256*4  = 65536
    float*          sums   = (float*)(ws + 327680);           // 65536
    int*            counts = (int*)(ws + 393216);             // 256

    setup_kernel<<<512 + 2 * NGRAPH, 256, 0, stream>>>(Wn1, Wn2, vx, bn1, batch,
                                                       wnt1x, wnt2, vc, sums, counts);
    node_kernel<<<NBLK, 512, 0, stream>>>(x, batch, wnt1x, vc, wnt2, bn2, hout, sums);
    vmlp1<<<NGRAPH, 256, 0, stream>>>(sums, counts, vx, Wv1, bv1, vout);
    vmlp2<<<NGRAPH, 256, 0, stream>>>(vout, Wv2, bv2, vout);
}